// Round 1
// baseline (745.377 us; speedup 1.0000x reference)
//
#include <hip/hip_runtime.h>
#include <hip/hip_bf16.h>

#define BB 4
#define CC 256
#define CI 128
#define NN 6272   // T*H*W = 8*28*28

typedef __attribute__((ext_vector_type(8))) __bf16 bf16x8;
typedef __attribute__((ext_vector_type(4))) __bf16 bf16x4;
typedef __attribute__((ext_vector_type(4))) float f32x4;

// ---------------- prep: fold weights/biases -> bf16, BN -> scale/shift ----------------
__global__ void nlb_prep(const float* __restrict__ Wg, const float* __restrict__ bg,
                         const float* __restrict__ Wt, const float* __restrict__ bt,
                         const float* __restrict__ Wp, const float* __restrict__ bp,
                         const float* __restrict__ Ww, const float* __restrict__ bw,
                         const float* __restrict__ gamma, const float* __restrict__ beta,
                         const float* __restrict__ rmean, const float* __restrict__ rvar,
                         __bf16* __restrict__ wall, float* __restrict__ ball,
                         __bf16* __restrict__ wwb, float* __restrict__ scale,
                         float* __restrict__ shift) {
  int idx = blockIdx.x * 256 + threadIdx.x;
  if (idx < 384 * 256) {
    int o = idx >> 8, c = idx & 255;
    float v, bv;
    if (o < 128)      { v = Wt[o * 256 + c];        bv = bt[o]; }
    else if (o < 256) { v = Wp[(o - 128) * 256 + c]; bv = bp[o - 128]; }
    else              { v = Wg[(o - 256) * 256 + c]; bv = bg[o - 256]; }
    wall[idx] = (__bf16)v;
    if (c == 0) ball[o] = bv;
  } else if (idx < 384 * 256 + 256 * 128) {
    int i = idx - 384 * 256;
    wwb[i] = (__bf16)Ww[i];
  } else if (idx < 384 * 256 + 256 * 128 + 256) {
    int c = idx - (384 * 256 + 256 * 128);
    float inv = gamma[c] * rsqrtf(rvar[c] + 1e-5f);
    scale[c] = inv;
    shift[c] = (bw[c] - rmean[c]) * inv + beta[c];
  }
}

// ---------------- projections: out[384][N] = Wall * x  (per batch), scattered stores ----------------
// Q  [B][N][CI]  (o in [0,128))
// Km [B][N][CI]  (o in [128,256))
// Vt [B][CI][N]  (o in [256,384))
__launch_bounds__(256)
__global__ void nlb_proj(const float* __restrict__ x, const __bf16* __restrict__ wall,
                         const float* __restrict__ ball,
                         __bf16* __restrict__ Q, __bf16* __restrict__ Km,
                         __bf16* __restrict__ Vt) {
  const int nb = blockIdx.x;          // 0..97
  const int mb = blockIdx.y;          // 0..5
  const int b  = blockIdx.z;          // 0..3
  const int tid = threadIdx.x;
  const int lane = tid & 63, w = tid >> 6;
  const int n0 = nb * 64;
  const int m0 = mb * 64 + w * 16;
  const int r = lane & 15, g = lane >> 4;

  __shared__ __bf16 xl[64][40];       // [n_local][k_local] bf16, pad to 40 (80B rows, 16B aligned)

  const float* xb = x + (size_t)b * CC * NN;
  f32x4 acc[4] = {};

  const int snn = tid & 63;           // staging: position
  const int skg = tid >> 6;           // staging: k-group (8 k's per wave)

  for (int k0 = 0; k0 < 256; k0 += 32) {
    bf16x8 tmp;
#pragma unroll
    for (int i = 0; i < 8; ++i)
      tmp[i] = (__bf16)xb[(size_t)(k0 + skg * 8 + i) * NN + n0 + snn];
    __syncthreads();                  // previous tile's readers done
    *reinterpret_cast<bf16x8*>(&xl[snn][skg * 8]) = tmp;
    __syncthreads();                  // writes visible

    bf16x8 afrag = *reinterpret_cast<const bf16x8*>(&wall[(size_t)(m0 + r) * 256 + k0 + g * 8]);
#pragma unroll
    for (int j = 0; j < 4; ++j) {
      bf16x8 bfrag = *reinterpret_cast<const bf16x8*>(&xl[j * 16 + r][g * 8]);
      acc[j] = __builtin_amdgcn_mfma_f32_16x16x32_bf16(afrag, bfrag, acc[j], 0, 0, 0);
    }
  }

  // epilogue: D[i][j]: row i = g*4+reg, col j = r  (m89 layout)
  if (m0 < 256) {
    __bf16* dst = (m0 < 128) ? Q : Km;
    const int obase = (m0 < 128) ? m0 : (m0 - 128);
#pragma unroll
    for (int j = 0; j < 4; ++j) {
      int n = n0 + j * 16 + r;
      bf16x4 pk;
#pragma unroll
      for (int reg = 0; reg < 4; ++reg) {
        int o = m0 + g * 4 + reg;
        pk[reg] = (__bf16)(acc[j][reg] + ball[o]);
      }
      *reinterpret_cast<bf16x4*>(&dst[((size_t)b * NN + n) * CI + obase + g * 4]) = pk;
    }
  } else {
#pragma unroll
    for (int j = 0; j < 4; ++j) {
      int n = n0 + j * 16 + r;
#pragma unroll
      for (int reg = 0; reg < 4; ++reg) {
        int o = m0 + g * 4 + reg;
        float v = acc[j][reg] + ball[o];
        Vt[((size_t)b * CI + (o - 256)) * NN + n] = (__bf16)v;
      }
    }
  }
}

// ---------------- flash attention: Y[b][n][ci] = softmax(Q K^T) V ----------------
__launch_bounds__(256)
__global__ void nlb_attn(const __bf16* __restrict__ Q, const __bf16* __restrict__ Km,
                         const __bf16* __restrict__ Vt, __bf16* __restrict__ Y) {
  const int qb = blockIdx.x;          // 0..97
  const int b  = blockIdx.y;          // 0..3
  const int tid = threadIdx.x, lane = tid & 63, w = tid >> 6;
  const int r = lane & 15, g = lane >> 4;
  const int q0 = qb * 64 + w * 16;

  const __bf16* Qb = Q  + (size_t)b * NN * CI;
  const __bf16* Kb = Km + (size_t)b * NN * CI;
  const __bf16* Vb = Vt + (size_t)b * CI * NN;

  __shared__ __bf16 plds[4][16][72];  // per-wave P tile [q_local][key_local], pad 72 (144B rows)

  bf16x8 qf[4];
#pragma unroll
  for (int kc = 0; kc < 4; ++kc)
    qf[kc] = *reinterpret_cast<const bf16x8*>(&Qb[(size_t)(q0 + r) * CI + kc * 32 + g * 8]);

  f32x4 yacc[8] = {};
  float m_r[4], l_r[4];
#pragma unroll
  for (int i = 0; i < 4; ++i) { m_r[i] = -1e30f; l_r[i] = 0.f; }

  for (int kv0 = 0; kv0 < NN; kv0 += 64) {
    f32x4 s[4] = {};
#pragma unroll
    for (int mt = 0; mt < 4; ++mt) {
#pragma unroll
      for (int kc = 0; kc < 4; ++kc) {
        bf16x8 kf = *reinterpret_cast<const bf16x8*>(
            &Kb[(size_t)(kv0 + mt * 16 + r) * CI + kc * 32 + g * 8]);
        s[mt] = __builtin_amdgcn_mfma_f32_16x16x32_bf16(qf[kc], kf, s[mt], 0, 0, 0);
      }
    }
    // online softmax row stats; row = g*4+reg lives on the 16 lanes of group g
    float alpha[4];
    float pv[4][4];
#pragma unroll
    for (int reg = 0; reg < 4; ++reg) {
      float tmax = fmaxf(fmaxf(s[0][reg], s[1][reg]), fmaxf(s[2][reg], s[3][reg]));
      tmax = fmaxf(tmax, __shfl_xor(tmax, 1));
      tmax = fmaxf(tmax, __shfl_xor(tmax, 2));
      tmax = fmaxf(tmax, __shfl_xor(tmax, 4));
      tmax = fmaxf(tmax, __shfl_xor(tmax, 8));
      float mnew = fmaxf(m_r[reg], tmax);
      alpha[reg] = __expf(m_r[reg] - mnew);
      m_r[reg] = mnew;
      float ps = 0.f;
#pragma unroll
      for (int mt = 0; mt < 4; ++mt) {
        float e = __expf(s[mt][reg] - mnew);
        pv[mt][reg] = e;
        ps += e;
      }
      ps += __shfl_xor(ps, 1); ps += __shfl_xor(ps, 2);
      ps += __shfl_xor(ps, 4); ps += __shfl_xor(ps, 8);
      l_r[reg] = l_r[reg] * alpha[reg] + ps;
    }
    // write P tile (bf16) — per-wave region, same-wave DS ordering, no barrier needed
#pragma unroll
    for (int mt = 0; mt < 4; ++mt)
#pragma unroll
      for (int reg = 0; reg < 4; ++reg)
        plds[w][g * 4 + reg][mt * 16 + r] = (__bf16)pv[mt][reg];
    // rescale accumulator
#pragma unroll
    for (int j = 0; j < 8; ++j)
#pragma unroll
      for (int reg = 0; reg < 4; ++reg)
        yacc[j][reg] *= alpha[reg];
    // PV
#pragma unroll
    for (int kc2 = 0; kc2 < 2; ++kc2) {
      bf16x8 pf = *reinterpret_cast<const bf16x8*>(&plds[w][r][kc2 * 32 + g * 8]);
#pragma unroll
      for (int j = 0; j < 8; ++j) {
        bf16x8 vf = *reinterpret_cast<const bf16x8*>(
            &Vb[(size_t)(j * 16 + r) * NN + kv0 + kc2 * 32 + g * 8]);
        yacc[j] = __builtin_amdgcn_mfma_f32_16x16x32_bf16(pf, vf, yacc[j], 0, 0, 0);
      }
    }
  }
  // normalize + store
#pragma unroll
  for (int j = 0; j < 8; ++j) {
#pragma unroll
    for (int reg = 0; reg < 4; ++reg) {
      int q = q0 + g * 4 + reg;
      float v = yacc[j][reg] / l_r[reg];
      Y[((size_t)b * NN + q) * CI + j * 16 + r] = (__bf16)v;
    }
  }
}

// ---------------- output: z = (Ww @ y)*scale + shift + x ----------------
__launch_bounds__(256)
__global__ void nlb_out(const __bf16* __restrict__ Y, const __bf16* __restrict__ wwb,
                        const float* __restrict__ scale, const float* __restrict__ shift,
                        const float* __restrict__ x, float* __restrict__ out) {
  const int nb = blockIdx.x;          // 0..97
  const int mb = blockIdx.y;          // 0..3
  const int b  = blockIdx.z;          // 0..3
  const int tid = threadIdx.x, lane = tid & 63, w = tid >> 6;
  const int r = lane & 15, g = lane >> 4;
  const int n0 = nb * 64, c0 = mb * 64 + w * 16;

  const __bf16* Yb = Y + (size_t)b * NN * CI;
  f32x4 acc[4] = {};
#pragma unroll
  for (int k0 = 0; k0 < 128; k0 += 32) {
    bf16x8 af = *reinterpret_cast<const bf16x8*>(&wwb[(size_t)(c0 + r) * CI + k0 + g * 8]);
#pragma unroll
    for (int j = 0; j < 4; ++j) {
      bf16x8 bfg = *reinterpret_cast<const bf16x8*>(
          &Yb[(size_t)(n0 + j * 16 + r) * CI + k0 + g * 8]);
      acc[j] = __builtin_amdgcn_mfma_f32_16x16x32_bf16(af, bfg, acc[j], 0, 0, 0);
    }
  }
  const float* xb = x + (size_t)b * CC * NN;
  float* ob = out + (size_t)b * CC * NN;
#pragma unroll
  for (int j = 0; j < 4; ++j) {
    int n = n0 + j * 16 + r;
#pragma unroll
    for (int reg = 0; reg < 4; ++reg) {
      int c = c0 + g * 4 + reg;
      size_t off = (size_t)c * NN + n;
      ob[off] = acc[j][reg] * scale[c] + shift[c] + xb[off];
    }
  }
}

extern "C" void kernel_launch(void* const* d_in, const int* in_sizes, int n_in,
                              void* d_out, int out_size, void* d_ws, size_t ws_size,
                              hipStream_t stream) {
  (void)in_sizes; (void)n_in; (void)out_size; (void)ws_size;
  const float* x     = (const float*)d_in[0];
  const float* Wg    = (const float*)d_in[1];
  const float* bg    = (const float*)d_in[2];
  const float* Wt    = (const float*)d_in[3];
  const float* bt    = (const float*)d_in[4];
  const float* Wp    = (const float*)d_in[5];
  const float* bp    = (const float*)d_in[6];
  const float* Ww    = (const float*)d_in[7];
  const float* bw    = (const float*)d_in[8];
  const float* gamma = (const float*)d_in[9];
  const float* beta  = (const float*)d_in[10];
  const float* rmean = (const float*)d_in[11];
  const float* rvar  = (const float*)d_in[12];
  float* out = (float*)d_out;

  char* ws = (char*)d_ws;
  __bf16* wall = (__bf16*)(ws + 0);                         // 384*256*2   = 196608
  float*  ball = (float*)(ws + 196608);                     // 384*4       = 1536
  __bf16* wwb  = (__bf16*)(ws + 198144);                    // 256*128*2   = 65536
  float*  scl  = (float*)(ws + 263680);                     // 256*4
  float*  shf  = (float*)(ws + 264704);                     // 256*4
  __bf16* Qw   = (__bf16*)(ws + 265728);                    // 4*6272*128*2 = 6422528
  __bf16* Kw   = (__bf16*)(ws + 265728 + 6422528ull);
  __bf16* Vw   = (__bf16*)(ws + 265728 + 2ull * 6422528ull);
  __bf16* Yw   = (__bf16*)(ws + 265728 + 3ull * 6422528ull);
  // total ws use ≈ 25.96 MB

  nlb_prep<<<513, 256, 0, stream>>>(Wg, bg, Wt, bt, Wp, bp, Ww, bw, gamma, beta,
                                    rmean, rvar, wall, ball, wwb, scl, shf);
  nlb_proj<<<dim3(98, 6, 4), 256, 0, stream>>>(x, wall, ball, Qw, Kw, Vw);
  nlb_attn<<<dim3(98, 4), 256, 0, stream>>>(Qw, Kw, Vw, Yw);
  nlb_out<<<dim3(98, 4, 4), 256, 0, stream>>>(Yw, wwb, scl, shf, x, out);
}

// Round 2
// 296.102 us; speedup vs baseline: 2.5173x; 2.5173x over previous
//
#include <hip/hip_runtime.h>
#include <hip/hip_bf16.h>

#define BB 4
#define CC 256
#define CI 128
#define NN 6272   // T*H*W = 8*28*28

typedef __attribute__((ext_vector_type(8))) __bf16 bf16x8;
typedef __attribute__((ext_vector_type(4))) __bf16 bf16x4;
typedef __attribute__((ext_vector_type(4))) float f32x4;

__device__ __forceinline__ void gll16(const void* g, void* l) {
  __builtin_amdgcn_global_load_lds(
      (const __attribute__((address_space(1))) void*)g,
      (__attribute__((address_space(3))) void*)l, 16, 0, 0);
}

// ---------------- prep: fold weights/biases -> bf16, BN -> scale/shift ----------------
__global__ void nlb_prep(const float* __restrict__ Wg, const float* __restrict__ bg,
                         const float* __restrict__ Wt, const float* __restrict__ bt,
                         const float* __restrict__ Wp, const float* __restrict__ bp,
                         const float* __restrict__ Ww, const float* __restrict__ bw,
                         const float* __restrict__ gamma, const float* __restrict__ beta,
                         const float* __restrict__ rmean, const float* __restrict__ rvar,
                         __bf16* __restrict__ wall, float* __restrict__ ball,
                         __bf16* __restrict__ wwb, float* __restrict__ scale,
                         float* __restrict__ shift) {
  int idx = blockIdx.x * 256 + threadIdx.x;
  if (idx < 384 * 256) {
    int o = idx >> 8, c = idx & 255;
    float v, bv;
    if (o < 128)      { v = Wt[o * 256 + c];        bv = bt[o]; }
    else if (o < 256) { v = Wp[(o - 128) * 256 + c]; bv = bp[o - 128]; }
    else              { v = Wg[(o - 256) * 256 + c]; bv = bg[o - 256]; }
    wall[idx] = (__bf16)v;
    if (c == 0) ball[o] = bv;
  } else if (idx < 384 * 256 + 256 * 128) {
    int i = idx - 384 * 256;
    wwb[i] = (__bf16)Ww[i];
  } else if (idx < 384 * 256 + 256 * 128 + 256) {
    int c = idx - (384 * 256 + 256 * 128);
    float inv = gamma[c] * rsqrtf(rvar[c] + 1e-5f);
    scale[c] = inv;
    shift[c] = (bw[c] - rmean[c]) * inv + beta[c];
  }
}

// ---------------- projections: out[384][N] = Wall * x  (per batch), scattered stores ----------------
__launch_bounds__(256)
__global__ void nlb_proj(const float* __restrict__ x, const __bf16* __restrict__ wall,
                         const float* __restrict__ ball,
                         __bf16* __restrict__ Q, __bf16* __restrict__ Km,
                         __bf16* __restrict__ Vt) {
  const int nb = blockIdx.x;          // 0..97
  const int mb = blockIdx.y;          // 0..5
  const int b  = blockIdx.z;          // 0..3
  const int tid = threadIdx.x;
  const int lane = tid & 63, w = tid >> 6;
  const int n0 = nb * 64;
  const int m0 = mb * 64 + w * 16;
  const int r = lane & 15, g = lane >> 4;

  __shared__ __bf16 xl[64][40];

  const float* xb = x + (size_t)b * CC * NN;
  f32x4 acc[4] = {};

  const int snn = tid & 63;
  const int skg = tid >> 6;

  for (int k0 = 0; k0 < 256; k0 += 32) {
    bf16x8 tmp;
#pragma unroll
    for (int i = 0; i < 8; ++i)
      tmp[i] = (__bf16)xb[(size_t)(k0 + skg * 8 + i) * NN + n0 + snn];
    __syncthreads();
    *reinterpret_cast<bf16x8*>(&xl[snn][skg * 8]) = tmp;
    __syncthreads();

    bf16x8 afrag = *reinterpret_cast<const bf16x8*>(&wall[(size_t)(m0 + r) * 256 + k0 + g * 8]);
#pragma unroll
    for (int j = 0; j < 4; ++j) {
      bf16x8 bfrag = *reinterpret_cast<const bf16x8*>(&xl[j * 16 + r][g * 8]);
      acc[j] = __builtin_amdgcn_mfma_f32_16x16x32_bf16(afrag, bfrag, acc[j], 0, 0, 0);
    }
  }

  if (m0 < 256) {
    __bf16* dst = (m0 < 128) ? Q : Km;
    const int obase = (m0 < 128) ? m0 : (m0 - 128);
#pragma unroll
    for (int j = 0; j < 4; ++j) {
      int n = n0 + j * 16 + r;
      bf16x4 pk;
#pragma unroll
      for (int reg = 0; reg < 4; ++reg) {
        int o = m0 + g * 4 + reg;
        pk[reg] = (__bf16)(acc[j][reg] + ball[o]);
      }
      *reinterpret_cast<bf16x4*>(&dst[((size_t)b * NN + n) * CI + obase + g * 4]) = pk;
    }
  } else {
#pragma unroll
    for (int j = 0; j < 4; ++j) {
      int n = n0 + j * 16 + r;
#pragma unroll
      for (int reg = 0; reg < 4; ++reg) {
        int o = m0 + g * 4 + reg;
        float v = acc[j][reg] + ball[o];
        Vt[((size_t)b * CI + (o - 256)) * NN + n] = (__bf16)v;
      }
    }
  }
}

// ---------------- flash attention with LDS-staged K/V, double-buffered ----------------
// K tile: 64 rows x 256B (swizzled col ^= (row&7)<<4), 16KB
// V tile: 128 rows x 128B (swizzled),                  16KB
__launch_bounds__(256)
__global__ void nlb_attn(const __bf16* __restrict__ Q, const __bf16* __restrict__ Km,
                         const __bf16* __restrict__ Vt, __bf16* __restrict__ Y) {
  const int bid = blockIdx.x;                 // 0..391
  const int swz = (bid & 7) * 49 + (bid >> 3); // 392 = 8*49 -> bijective XCD swizzle
  const int b  = swz / 98;
  const int qb = swz % 98;
  const int tid = threadIdx.x, lane = tid & 63, w = tid >> 6;
  const int r = lane & 15, g = lane >> 4;
  const int q0 = qb * 64 + w * 16;

  const __bf16* Qb = Q  + (size_t)b * NN * CI;
  const char*   Kc = (const char*)(Km + (size_t)b * NN * CI);
  const char*   Vc = (const char*)(Vt + (size_t)b * CI * NN);

  __shared__ __bf16 KL[2][8192];
  __shared__ __bf16 VL[2][8192];
  __shared__ __bf16 plds[4][16][72];

  // staging source addresses (pre-swizzled global so linear LDS == swizzled layout)
  const char* ks[4];
  const char* vs[4];
#pragma unroll
  for (int i = 0; i < 4; ++i) {
    int p = (w * 4 + i) * 1024 + lane * 16;
    int kr = p >> 8, kcl = p & 255;
    ks[i] = Kc + (size_t)kr * 256 + (kcl ^ ((kr & 7) << 4));
    int vr = p >> 7, vcl = p & 127;
    vs[i] = Vc + (size_t)vr * (NN * 2) + (vcl ^ ((vr & 7) << 4));
  }

  auto stage = [&](int bb, int t) {
    size_t ko = (size_t)t << 14;   // t * 16384 bytes (64 rows * 256B)
    size_t vo = (size_t)t << 7;    // t * 128 bytes (64 kv * 2B)
#pragma unroll
    for (int i = 0; i < 4; ++i) {
      gll16(ks[i] + ko, &KL[bb][(w * 4 + i) * 512]);
      gll16(vs[i] + vo, &VL[bb][(w * 4 + i) * 512]);
    }
  };

  // Q fragments (16 rows per wave), stay in registers
  bf16x8 qf[4];
#pragma unroll
  for (int kc = 0; kc < 4; ++kc)
    qf[kc] = *reinterpret_cast<const bf16x8*>(&Qb[(size_t)(q0 + r) * CI + kc * 32 + g * 8]);

  const int rx = (r & 7) << 4;
  int ck[4], cv[2];
#pragma unroll
  for (int kc = 0; kc < 4; ++kc) ck[kc] = (kc * 64 + g * 16) ^ rx;
#pragma unroll
  for (int kc = 0; kc < 2; ++kc) cv[kc] = (kc * 64 + g * 16) ^ rx;

  f32x4 yacc[8] = {};
  float m_r[4], l_r[4];
#pragma unroll
  for (int i = 0; i < 4; ++i) { m_r[i] = -1e30f; l_r[i] = 0.f; }

  stage(0, 0);
  __syncthreads();                 // implicit vmcnt(0) drain completes staging

  int buf = 0;
  for (int t = 0; t < 98; ++t) {
    if (t + 1 < 98) stage(buf ^ 1, t + 1);   // prefetch next tile (overlaps compute)

    // ---- QK^T from LDS ----
    f32x4 s[4] = {};
    __builtin_amdgcn_s_setprio(1);
#pragma unroll
    for (int kc = 0; kc < 4; ++kc) {
#pragma unroll
      for (int mt = 0; mt < 4; ++mt) {
        bf16x8 kf = *reinterpret_cast<const bf16x8*>(
            &KL[buf][(((mt * 16 + r) << 8) + ck[kc]) >> 1]);
        s[mt] = __builtin_amdgcn_mfma_f32_16x16x32_bf16(qf[kc], kf, s[mt], 0, 0, 0);
      }
    }
    __builtin_amdgcn_s_setprio(0);

    // ---- online softmax (row = g*4+reg on the 16 lanes of group g) ----
    float alpha[4];
    float pv[4][4];
#pragma unroll
    for (int reg = 0; reg < 4; ++reg) {
      float tmax = fmaxf(fmaxf(s[0][reg], s[1][reg]), fmaxf(s[2][reg], s[3][reg]));
      tmax = fmaxf(tmax, __shfl_xor(tmax, 1));
      tmax = fmaxf(tmax, __shfl_xor(tmax, 2));
      tmax = fmaxf(tmax, __shfl_xor(tmax, 4));
      tmax = fmaxf(tmax, __shfl_xor(tmax, 8));
      float mnew = fmaxf(m_r[reg], tmax);
      alpha[reg] = __expf(m_r[reg] - mnew);
      m_r[reg] = mnew;
      float ps = 0.f;
#pragma unroll
      for (int mt = 0; mt < 4; ++mt) {
        float e = __expf(s[mt][reg] - mnew);
        pv[mt][reg] = e;
        ps += e;
      }
      ps += __shfl_xor(ps, 1); ps += __shfl_xor(ps, 2);
      ps += __shfl_xor(ps, 4); ps += __shfl_xor(ps, 8);
      l_r[reg] = l_r[reg] * alpha[reg] + ps;
    }

    // P tile -> per-wave LDS (same-wave ordering, no barrier)
#pragma unroll
    for (int mt = 0; mt < 4; ++mt)
#pragma unroll
      for (int reg = 0; reg < 4; ++reg)
        plds[w][g * 4 + reg][mt * 16 + r] = (__bf16)pv[mt][reg];

    // rescale accumulator
#pragma unroll
    for (int j = 0; j < 8; ++j)
#pragma unroll
      for (int reg = 0; reg < 4; ++reg)
        yacc[j][reg] *= alpha[reg];

    // ---- PV from LDS ----
    __builtin_amdgcn_s_setprio(1);
#pragma unroll
    for (int kc2 = 0; kc2 < 2; ++kc2) {
      bf16x8 pf = *reinterpret_cast<const bf16x8*>(&plds[w][r][kc2 * 32 + g * 8]);
#pragma unroll
      for (int j = 0; j < 8; ++j) {
        bf16x8 vf = *reinterpret_cast<const bf16x8*>(
            &VL[buf][(((j * 16 + r) << 7) + cv[kc2]) >> 1]);
        yacc[j] = __builtin_amdgcn_mfma_f32_16x16x32_bf16(pf, vf, yacc[j], 0, 0, 0);
      }
    }
    __builtin_amdgcn_s_setprio(0);

    __syncthreads();               // drains stage loads; all waves done reading buf
    buf ^= 1;
  }

  // normalize + store
#pragma unroll
  for (int j = 0; j < 8; ++j) {
#pragma unroll
    for (int reg = 0; reg < 4; ++reg) {
      int q = q0 + g * 4 + reg;
      float v = yacc[j][reg] / l_r[reg];
      Y[((size_t)b * NN + q) * CI + j * 16 + r] = (__bf16)v;
    }
  }
}

// ---------------- output: z = (Ww @ y)*scale + shift + x ----------------
__launch_bounds__(256)
__global__ void nlb_out(const __bf16* __restrict__ Y, const __bf16* __restrict__ wwb,
                        const float* __restrict__ scale, const float* __restrict__ shift,
                        const float* __restrict__ x, float* __restrict__ out) {
  const int nb = blockIdx.x;
  const int mb = blockIdx.y;
  const int b  = blockIdx.z;
  const int tid = threadIdx.x, lane = tid & 63, w = tid >> 6;
  const int r = lane & 15, g = lane >> 4;
  const int n0 = nb * 64, c0 = mb * 64 + w * 16;

  const __bf16* Yb = Y + (size_t)b * NN * CI;
  f32x4 acc[4] = {};
#pragma unroll
  for (int k0 = 0; k0 < 128; k0 += 32) {
    bf16x8 af = *reinterpret_cast<const bf16x8*>(&wwb[(size_t)(c0 + r) * CI + k0 + g * 8]);
#pragma unroll
    for (int j = 0; j < 4; ++j) {
      bf16x8 bfg = *reinterpret_cast<const bf16x8*>(
          &Yb[(size_t)(n0 + j * 16 + r) * CI + k0 + g * 8]);
      acc[j] = __builtin_amdgcn_mfma_f32_16x16x32_bf16(af, bfg, acc[j], 0, 0, 0);
    }
  }
  const float* xb = x + (size_t)b * CC * NN;
  float* ob = out + (size_t)b * CC * NN;
#pragma unroll
  for (int j = 0; j < 4; ++j) {
    int n = n0 + j * 16 + r;
#pragma unroll
    for (int reg = 0; reg < 4; ++reg) {
      int c = c0 + g * 4 + reg;
      size_t off = (size_t)c * NN + n;
      ob[off] = acc[j][reg] * scale[c] + shift[c] + xb[off];
    }
  }
}

extern "C" void kernel_launch(void* const* d_in, const int* in_sizes, int n_in,
                              void* d_out, int out_size, void* d_ws, size_t ws_size,
                              hipStream_t stream) {
  (void)in_sizes; (void)n_in; (void)out_size; (void)ws_size;
  const float* x     = (const float*)d_in[0];
  const float* Wg    = (const float*)d_in[1];
  const float* bg    = (const float*)d_in[2];
  const float* Wt    = (const float*)d_in[3];
  const float* bt    = (const float*)d_in[4];
  const float* Wp    = (const float*)d_in[5];
  const float* bp    = (const float*)d_in[6];
  const float* Ww    = (const float*)d_in[7];
  const float* bw    = (const float*)d_in[8];
  const float* gamma = (const float*)d_in[9];
  const float* beta  = (const float*)d_in[10];
  const float* rmean = (const float*)d_in[11];
  const float* rvar  = (const float*)d_in[12];
  float* out = (float*)d_out;

  char* ws = (char*)d_ws;
  __bf16* wall = (__bf16*)(ws + 0);
  float*  ball = (float*)(ws + 196608);
  __bf16* wwb  = (__bf16*)(ws + 198144);
  float*  scl  = (float*)(ws + 263680);
  float*  shf  = (float*)(ws + 264704);
  __bf16* Qw   = (__bf16*)(ws + 265728);
  __bf16* Kw   = (__bf16*)(ws + 265728 + 6422528ull);
  __bf16* Vw   = (__bf16*)(ws + 265728 + 2ull * 6422528ull);
  __bf16* Yw   = (__bf16*)(ws + 265728 + 3ull * 6422528ull);

  nlb_prep<<<513, 256, 0, stream>>>(Wg, bg, Wt, bt, Wp, bp, Ww, bw, gamma, beta,
                                    rmean, rvar, wall, ball, wwb, scl, shf);
  nlb_proj<<<dim3(98, 6, 4), 256, 0, stream>>>(x, wall, ball, Qw, Kw, Vw);
  nlb_attn<<<392, 256, 0, stream>>>(Qw, Kw, Vw, Yw);
  nlb_out<<<dim3(98, 4, 4), 256, 0, stream>>>(Yw, wwb, scl, shf, x, out);
}

// Round 3
// 228.674 us; speedup vs baseline: 3.2596x; 1.2949x over previous
//
#include <hip/hip_runtime.h>
#include <hip/hip_bf16.h>

#define BB 4
#define CC 256
#define CI 128
#define NN 6272   // T*H*W = 8*28*28
#define LOG2E 1.4426950408889634f

typedef __attribute__((ext_vector_type(8))) __bf16 bf16x8;
typedef __attribute__((ext_vector_type(4))) __bf16 bf16x4;
typedef __attribute__((ext_vector_type(4))) float f32x4;

__device__ __forceinline__ void gll16(const void* g, void* l) {
  __builtin_amdgcn_global_load_lds(
      (const __attribute__((address_space(1))) void*)g,
      (__attribute__((address_space(3))) void*)l, 16, 0, 0);
}

// ---------------- prep: fold weights/biases -> bf16, BN -> scale/shift ----------------
// Wt/bt are pre-scaled by log2(e) so attention logits are in log2 units.
__global__ void nlb_prep(const float* __restrict__ Wg, const float* __restrict__ bg,
                         const float* __restrict__ Wt, const float* __restrict__ bt,
                         const float* __restrict__ Wp, const float* __restrict__ bp,
                         const float* __restrict__ Ww, const float* __restrict__ bw,
                         const float* __restrict__ gamma, const float* __restrict__ beta,
                         const float* __restrict__ rmean, const float* __restrict__ rvar,
                         __bf16* __restrict__ wall, float* __restrict__ ball,
                         __bf16* __restrict__ wwb, float* __restrict__ scale,
                         float* __restrict__ shift) {
  int idx = blockIdx.x * 256 + threadIdx.x;
  if (idx < 384 * 256) {
    int o = idx >> 8, c = idx & 255;
    float v, bv;
    if (o < 128)      { v = Wt[o * 256 + c] * LOG2E;  bv = bt[o] * LOG2E; }
    else if (o < 256) { v = Wp[(o - 128) * 256 + c]; bv = bp[o - 128]; }
    else              { v = Wg[(o - 256) * 256 + c]; bv = bg[o - 256]; }
    wall[idx] = (__bf16)v;
    if (c == 0) ball[o] = bv;
  } else if (idx < 384 * 256 + 256 * 128) {
    int i = idx - 384 * 256;
    wwb[i] = (__bf16)Ww[i];
  } else if (idx < 384 * 256 + 256 * 128 + 256) {
    int c = idx - (384 * 256 + 256 * 128);
    float inv = gamma[c] * rsqrtf(rvar[c] + 1e-5f);
    scale[c] = inv;
    shift[c] = (bw[c] - rmean[c]) * inv + beta[c];
  }
}

// ---------------- projections ----------------
__launch_bounds__(256)
__global__ void nlb_proj(const float* __restrict__ x, const __bf16* __restrict__ wall,
                         const float* __restrict__ ball,
                         __bf16* __restrict__ Q, __bf16* __restrict__ Km,
                         __bf16* __restrict__ Vt) {
  const int nb = blockIdx.x;
  const int mb = blockIdx.y;
  const int b  = blockIdx.z;
  const int tid = threadIdx.x;
  const int lane = tid & 63, w = tid >> 6;
  const int n0 = nb * 64;
  const int m0 = mb * 64 + w * 16;
  const int r = lane & 15, g = lane >> 4;

  __shared__ __bf16 xl[64][40];

  const float* xb = x + (size_t)b * CC * NN;
  f32x4 acc[4] = {};

  const int snn = tid & 63;
  const int skg = tid >> 6;

  for (int k0 = 0; k0 < 256; k0 += 32) {
    bf16x8 tmp;
#pragma unroll
    for (int i = 0; i < 8; ++i)
      tmp[i] = (__bf16)xb[(size_t)(k0 + skg * 8 + i) * NN + n0 + snn];
    __syncthreads();
    *reinterpret_cast<bf16x8*>(&xl[snn][skg * 8]) = tmp;
    __syncthreads();

    bf16x8 afrag = *reinterpret_cast<const bf16x8*>(&wall[(size_t)(m0 + r) * 256 + k0 + g * 8]);
#pragma unroll
    for (int j = 0; j < 4; ++j) {
      bf16x8 bfrag = *reinterpret_cast<const bf16x8*>(&xl[j * 16 + r][g * 8]);
      acc[j] = __builtin_amdgcn_mfma_f32_16x16x32_bf16(afrag, bfrag, acc[j], 0, 0, 0);
    }
  }

  if (m0 < 256) {
    __bf16* dst = (m0 < 128) ? Q : Km;
    const int obase = (m0 < 128) ? m0 : (m0 - 128);
#pragma unroll
    for (int j = 0; j < 4; ++j) {
      int n = n0 + j * 16 + r;
      bf16x4 pk;
#pragma unroll
      for (int reg = 0; reg < 4; ++reg) {
        int o = m0 + g * 4 + reg;
        pk[reg] = (__bf16)(acc[j][reg] + ball[o]);
      }
      *reinterpret_cast<bf16x4*>(&dst[((size_t)b * NN + n) * CI + obase + g * 4]) = pk;
    }
  } else {
#pragma unroll
    for (int j = 0; j < 4; ++j) {
      int n = n0 + j * 16 + r;
#pragma unroll
      for (int reg = 0; reg < 4; ++reg) {
        int o = m0 + g * 4 + reg;
        float v = acc[j][reg] + ball[o];
        Vt[((size_t)b * CI + (o - 256)) * NN + n] = (__bf16)v;
      }
    }
  }
}

// ---------------- flash attention: 8 waves, key-split halves, swapped QK^T ----------------
__launch_bounds__(512, 4)
__global__ void nlb_attn(const __bf16* __restrict__ Q, const __bf16* __restrict__ Km,
                         const __bf16* __restrict__ Vt, __bf16* __restrict__ Y) {
  const int bid = blockIdx.x;                  // 0..391
  const int swz = (bid & 7) * 49 + (bid >> 3); // bijective XCD swizzle (392 = 8*49)
  const int b  = swz / 98;
  const int qb = swz % 98;
  const int tid = threadIdx.x, lane = tid & 63, w = tid >> 6;
  const int r = lane & 15, g = lane >> 4;
  const int wq = w & 3, h = w >> 2;            // q-wave, key-half
  const int q0 = qb * 64 + wq * 16;
  const int rx = (r & 7) << 4;

  const __bf16* Qb = Q  + (size_t)b * NN * CI;
  const char*   Kc = (const char*)(Km + (size_t)b * NN * CI);
  const char*   Vc = (const char*)(Vt + (size_t)b * CI * NN);

  __shared__ __align__(16) char sm[65536];               // KL[2]:32KB  VL[2]:32KB
  __shared__ __align__(16) __bf16 plds[8][16][40];       // per-wave P tile, 80B rows

  // staging source addresses (pre-swizzled global so linear LDS == swizzled layout)
  const char* ks[2]; const char* vs[2];
#pragma unroll
  for (int i = 0; i < 2; ++i) {
    int p = (w * 2 + i) * 1024 + lane * 16;
    int kr = p >> 8, kcl = p & 255;
    ks[i] = Kc + (size_t)kr * 256 + (kcl ^ ((kr & 7) << 4));
    int vr = p >> 7, vcl = p & 127;
    vs[i] = Vc + (size_t)vr * (NN * 2) + (vcl ^ ((vr & 7) << 4));
  }

  auto stage = [&](int bb, int t) {
    size_t ko = (size_t)t << 14;   // t * 16384 B
    size_t vo = (size_t)t << 7;    // t * 128 B
    char* kl = sm + bb * 16384;
    char* vl = sm + 32768 + bb * 16384;
#pragma unroll
    for (int i = 0; i < 2; ++i) {
      gll16(ks[i] + ko, kl + (w * 2 + i) * 1024);
      gll16(vs[i] + vo, vl + (w * 2 + i) * 1024);
    }
  };

  // Q fragments (B operand): lane r holds Q row q0+r
  bf16x8 qf[4];
#pragma unroll
  for (int kc = 0; kc < 4; ++kc)
    qf[kc] = *reinterpret_cast<const bf16x8*>(&Qb[(size_t)(q0 + r) * CI + kc * 32 + g * 8]);

  f32x4 yacc[8] = {};
  float m_r = -1e30f, l_r = 0.f;   // per-lane state for q = q0 + r (replicated over groups)

  stage(0, 0);
  __syncthreads();

  int buf = 0;
  char* pw = (char*)&plds[w][0][0];
  for (int t = 0; t < 98; ++t) {
    if (t + 1 < 98) stage(buf ^ 1, t + 1);
    const char* kl = sm + buf * 16384;
    const char* vl = sm + 32768 + buf * 16384;

    // ---- QK^T swapped: D[key][q] ----
    f32x4 s[2] = {};
    __builtin_amdgcn_s_setprio(1);
#pragma unroll
    for (int kc = 0; kc < 4; ++kc) {
#pragma unroll
      for (int mt = 0; mt < 2; ++mt) {
        bf16x8 kf = *reinterpret_cast<const bf16x8*>(
            kl + (h * 32 + mt * 16 + r) * 256 + ((kc * 64 + g * 16) ^ rx));
        s[mt] = __builtin_amdgcn_mfma_f32_16x16x32_bf16(kf, qf[kc], s[mt], 0, 0, 0);
      }
    }
    __builtin_amdgcn_s_setprio(0);

    // ---- softmax (logits already in log2 units): lane holds 8 keys for q=q0+r ----
    float t0 = fmaxf(fmaxf(s[0][0], s[0][1]), fmaxf(s[0][2], s[0][3]));
    float t1 = fmaxf(fmaxf(s[1][0], s[1][1]), fmaxf(s[1][2], s[1][3]));
    float tmax = fmaxf(t0, t1);
    tmax = fmaxf(tmax, __shfl_xor(tmax, 16));
    tmax = fmaxf(tmax, __shfl_xor(tmax, 32));

    if (!__all(tmax <= m_r + 8.f)) {          // defer-max: rescale only on real growth
      float mnew = fmaxf(m_r, tmax);
      float al = exp2f(m_r - mnew);
      m_r = mnew;
      l_r *= al;
      float a0 = __shfl(al, g * 4 + 0), a1 = __shfl(al, g * 4 + 1);
      float a2 = __shfl(al, g * 4 + 2), a3 = __shfl(al, g * 4 + 3);
#pragma unroll
      for (int j = 0; j < 8; ++j) {
        yacc[j][0] *= a0; yacc[j][1] *= a1; yacc[j][2] *= a2; yacc[j][3] *= a3;
      }
    }

    float p[8];
    float ps = 0.f;
#pragma unroll
    for (int mt = 0; mt < 2; ++mt)
#pragma unroll
      for (int reg = 0; reg < 4; ++reg) {
        float e = exp2f(s[mt][reg] - m_r);
        p[mt * 4 + reg] = e;
        ps += e;
      }
    ps += __shfl_xor(ps, 16);
    ps += __shfl_xor(ps, 32);
    l_r += ps;

    // ---- P -> per-wave LDS (packed b32 writes), then PV ----
#pragma unroll
    for (int mt = 0; mt < 2; ++mt)
#pragma unroll
      for (int d = 0; d < 2; ++d) {
        union { unsigned u; __bf16 hh[2]; } pk;
        pk.hh[0] = (__bf16)p[mt * 4 + 2 * d];
        pk.hh[1] = (__bf16)p[mt * 4 + 2 * d + 1];
        *reinterpret_cast<unsigned*>(pw + r * 80 + mt * 32 + g * 8 + d * 4) = pk.u;
      }

    bf16x8 pf = *reinterpret_cast<const bf16x8*>(pw + r * 80 + g * 16);
    __builtin_amdgcn_s_setprio(1);
#pragma unroll
    for (int j = 0; j < 8; ++j) {
      bf16x8 vf = *reinterpret_cast<const bf16x8*>(
          vl + (j * 16 + r) * 128 + ((h * 64 + g * 16) ^ rx));
      yacc[j] = __builtin_amdgcn_mfma_f32_16x16x32_bf16(pf, vf, yacc[j], 0, 0, 0);
    }
    __builtin_amdgcn_s_setprio(0);

    __syncthreads();
    buf ^= 1;
  }

  // ---- merge key-halves (waves w and w+4 share q rows) ----
  float* scr = (float*)sm;   // reuse staging LDS
  __syncthreads();
  if (h == 1) {
    float* base = scr + (size_t)wq * 64 * 34 + lane * 34;
#pragma unroll
    for (int j = 0; j < 8; ++j)
#pragma unroll
      for (int reg = 0; reg < 4; ++reg) base[j * 4 + reg] = yacc[j][reg];
    base[32] = m_r;
    base[33] = l_r;
  }
  __syncthreads();
  if (h == 0) {
    const float* base = scr + (size_t)wq * 64 * 34 + lane * 34;
    float mB = base[32], lB = base[33];
    float mM = fmaxf(m_r, mB);
    float fA = exp2f(m_r - mM);
    float fB = exp2f(mB - mM);
    float lM = l_r * fA + lB * fB;
    float fa[4], fb[4], lm[4];
#pragma unroll
    for (int reg = 0; reg < 4; ++reg) {
      fa[reg] = __shfl(fA, g * 4 + reg);
      fb[reg] = __shfl(fB, g * 4 + reg);
      lm[reg] = __shfl(lM, g * 4 + reg);
    }
#pragma unroll
    for (int j = 0; j < 8; ++j) {
#pragma unroll
      for (int reg = 0; reg < 4; ++reg) {
        int q = q0 + g * 4 + reg;
        float v = (yacc[j][reg] * fa[reg] + base[j * 4 + reg] * fb[reg]) / lm[reg];
        Y[((size_t)b * NN + q) * CI + j * 16 + r] = (__bf16)v;
      }
    }
  }
}

// ---------------- output: z = (Ww @ y)*scale + shift + x ----------------
__launch_bounds__(256)
__global__ void nlb_out(const __bf16* __restrict__ Y, const __bf16* __restrict__ wwb,
                        const float* __restrict__ scale, const float* __restrict__ shift,
                        const float* __restrict__ x, float* __restrict__ out) {
  const int nb = blockIdx.x;
  const int mb = blockIdx.y;
  const int b  = blockIdx.z;
  const int tid = threadIdx.x, lane = tid & 63, w = tid >> 6;
  const int r = lane & 15, g = lane >> 4;
  const int n0 = nb * 64, c0 = mb * 64 + w * 16;

  const __bf16* Yb = Y + (size_t)b * NN * CI;
  f32x4 acc[4] = {};
#pragma unroll
  for (int k0 = 0; k0 < 128; k0 += 32) {
    bf16x8 af = *reinterpret_cast<const bf16x8*>(&wwb[(size_t)(c0 + r) * CI + k0 + g * 8]);
#pragma unroll
    for (int j = 0; j < 4; ++j) {
      bf16x8 bfg = *reinterpret_cast<const bf16x8*>(
          &Yb[(size_t)(n0 + j * 16 + r) * CI + k0 + g * 8]);
      acc[j] = __builtin_amdgcn_mfma_f32_16x16x32_bf16(af, bfg, acc[j], 0, 0, 0);
    }
  }
  const float* xb = x + (size_t)b * CC * NN;
  float* ob = out + (size_t)b * CC * NN;
#pragma unroll
  for (int j = 0; j < 4; ++j) {
    int n = n0 + j * 16 + r;
#pragma unroll
    for (int reg = 0; reg < 4; ++reg) {
      int c = c0 + g * 4 + reg;
      size_t off = (size_t)c * NN + n;
      ob[off] = acc[j][reg] * scale[c] + shift[c] + xb[off];
    }
  }
}

extern "C" void kernel_launch(void* const* d_in, const int* in_sizes, int n_in,
                              void* d_out, int out_size, void* d_ws, size_t ws_size,
                              hipStream_t stream) {
  (void)in_sizes; (void)n_in; (void)out_size; (void)ws_size;
  const float* x     = (const float*)d_in[0];
  const float* Wg    = (const float*)d_in[1];
  const float* bg    = (const float*)d_in[2];
  const float* Wt    = (const float*)d_in[3];
  const float* bt    = (const float*)d_in[4];
  const float* Wp    = (const float*)d_in[5];
  const float* bp    = (const float*)d_in[6];
  const float* Ww    = (const float*)d_in[7];
  const float* bw    = (const float*)d_in[8];
  const float* gamma = (const float*)d_in[9];
  const float* beta  = (const float*)d_in[10];
  const float* rmean = (const float*)d_in[11];
  const float* rvar  = (const float*)d_in[12];
  float* out = (float*)d_out;

  char* ws = (char*)d_ws;
  __bf16* wall = (__bf16*)(ws + 0);
  float*  ball = (float*)(ws + 196608);
  __bf16* wwb  = (__bf16*)(ws + 198144);
  float*  scl  = (float*)(ws + 263680);
  float*  shf  = (float*)(ws + 264704);
  __bf16* Qw   = (__bf16*)(ws + 265728);
  __bf16* Kw   = (__bf16*)(ws + 265728 + 6422528ull);
  __bf16* Vw   = (__bf16*)(ws + 265728 + 2ull * 6422528ull);
  __bf16* Yw   = (__bf16*)(ws + 265728 + 3ull * 6422528ull);

  nlb_prep<<<513, 256, 0, stream>>>(Wg, bg, Wt, bt, Wp, bp, Ww, bw, gamma, beta,
                                    rmean, rvar, wall, ball, wwb, scl, shf);
  nlb_proj<<<dim3(98, 6, 4), 256, 0, stream>>>(x, wall, ball, Qw, Kw, Vw);
  nlb_attn<<<392, 512, 0, stream>>>(Qw, Kw, Vw, Yw);
  nlb_out<<<dim3(98, 4, 4), 256, 0, stream>>>(Yw, wwb, scl, shf, x, out);
}

// Round 4
// 217.680 us; speedup vs baseline: 3.4242x; 1.0505x over previous
//
#include <hip/hip_runtime.h>
#include <hip/hip_bf16.h>

#define BB 4
#define CC 256
#define CI 128
#define NN 6272   // T*H*W = 8*28*28
#define LOG2E 1.4426950408889634f

typedef __attribute__((ext_vector_type(8))) __bf16 bf16x8;
typedef __attribute__((ext_vector_type(4))) __bf16 bf16x4;
typedef __attribute__((ext_vector_type(4))) float f32x4;
typedef __attribute__((ext_vector_type(16))) float f32x16;

__device__ __forceinline__ void gll16(const void* g, void* l) {
  __builtin_amdgcn_global_load_lds(
      (const __attribute__((address_space(1))) void*)g,
      (__attribute__((address_space(3))) void*)l, 16, 0, 0);
}

__device__ __forceinline__ unsigned cvtpk(float a, float b) {
  unsigned r;
  asm("v_cvt_pk_bf16_f32 %0, %1, %2" : "=v"(r) : "v"(a), "v"(b));
  return r;
}

// ---------------- prep: fold weights/biases -> bf16, BN -> scale/shift ----------------
// Wt/bt pre-scaled by log2(e) so attention logits are in log2 units.
__global__ void nlb_prep(const float* __restrict__ Wg, const float* __restrict__ bg,
                         const float* __restrict__ Wt, const float* __restrict__ bt,
                         const float* __restrict__ Wp, const float* __restrict__ bp,
                         const float* __restrict__ Ww, const float* __restrict__ bw,
                         const float* __restrict__ gamma, const float* __restrict__ beta,
                         const float* __restrict__ rmean, const float* __restrict__ rvar,
                         __bf16* __restrict__ wall, float* __restrict__ ball,
                         __bf16* __restrict__ wwb, float* __restrict__ scale,
                         float* __restrict__ shift) {
  int idx = blockIdx.x * 256 + threadIdx.x;
  if (idx < 384 * 256) {
    int o = idx >> 8, c = idx & 255;
    float v, bv;
    if (o < 128)      { v = Wt[o * 256 + c] * LOG2E;  bv = bt[o] * LOG2E; }
    else if (o < 256) { v = Wp[(o - 128) * 256 + c]; bv = bp[o - 128]; }
    else              { v = Wg[(o - 256) * 256 + c]; bv = bg[o - 256]; }
    wall[idx] = (__bf16)v;
    if (c == 0) ball[o] = bv;
  } else if (idx < 384 * 256 + 256 * 128) {
    int i = idx - 384 * 256;
    wwb[i] = (__bf16)Ww[i];
  } else if (idx < 384 * 256 + 256 * 128 + 256) {
    int c = idx - (384 * 256 + 256 * 128);
    float inv = gamma[c] * rsqrtf(rvar[c] + 1e-5f);
    scale[c] = inv;
    shift[c] = (bw[c] - rmean[c]) * inv + beta[c];
  }
}

// ---------------- projections ----------------
__launch_bounds__(256)
__global__ void nlb_proj(const float* __restrict__ x, const __bf16* __restrict__ wall,
                         const float* __restrict__ ball,
                         __bf16* __restrict__ Q, __bf16* __restrict__ Km,
                         __bf16* __restrict__ Vt) {
  const int nb = blockIdx.x;
  const int mb = blockIdx.y;
  const int b  = blockIdx.z;
  const int tid = threadIdx.x;
  const int lane = tid & 63, w = tid >> 6;
  const int n0 = nb * 64;
  const int m0 = mb * 64 + w * 16;
  const int r = lane & 15, g = lane >> 4;

  __shared__ __bf16 xl[64][40];

  const float* xb = x + (size_t)b * CC * NN;
  f32x4 acc[4] = {};

  const int snn = tid & 63;
  const int skg = tid >> 6;

  for (int k0 = 0; k0 < 256; k0 += 32) {
    bf16x8 tmp;
#pragma unroll
    for (int i = 0; i < 8; ++i)
      tmp[i] = (__bf16)xb[(size_t)(k0 + skg * 8 + i) * NN + n0 + snn];
    __syncthreads();
    *reinterpret_cast<bf16x8*>(&xl[snn][skg * 8]) = tmp;
    __syncthreads();

    bf16x8 afrag = *reinterpret_cast<const bf16x8*>(&wall[(size_t)(m0 + r) * 256 + k0 + g * 8]);
#pragma unroll
    for (int j = 0; j < 4; ++j) {
      bf16x8 bfrag = *reinterpret_cast<const bf16x8*>(&xl[j * 16 + r][g * 8]);
      acc[j] = __builtin_amdgcn_mfma_f32_16x16x32_bf16(afrag, bfrag, acc[j], 0, 0, 0);
    }
  }

  if (m0 < 256) {
    __bf16* dst = (m0 < 128) ? Q : Km;
    const int obase = (m0 < 128) ? m0 : (m0 - 128);
#pragma unroll
    for (int j = 0; j < 4; ++j) {
      int n = n0 + j * 16 + r;
      bf16x4 pk;
#pragma unroll
      for (int reg = 0; reg < 4; ++reg) {
        int o = m0 + g * 4 + reg;
        pk[reg] = (__bf16)(acc[j][reg] + ball[o]);
      }
      *reinterpret_cast<bf16x4*>(&dst[((size_t)b * NN + n) * CI + obase + g * 4]) = pk;
    }
  } else {
#pragma unroll
    for (int j = 0; j < 4; ++j) {
      int n = n0 + j * 16 + r;
#pragma unroll
      for (int reg = 0; reg < 4; ++reg) {
        int o = m0 + g * 4 + reg;
        float v = acc[j][reg] + ball[o];
        Vt[((size_t)b * CI + (o - 256)) * NN + n] = (__bf16)v;
      }
    }
  }
}

// ---------------- flash attention: 32x32 MFMA, 4 waves (2 q-groups x 2 key-halves) ----------------
__launch_bounds__(256, 2)
__global__ void nlb_attn(const __bf16* __restrict__ Q, const __bf16* __restrict__ Km,
                         const __bf16* __restrict__ Vt, __bf16* __restrict__ Y) {
  const int bid = blockIdx.x;                  // 0..391
  const int swz = (bid & 7) * 49 + (bid >> 3); // bijective XCD swizzle (392 = 8*49)
  const int b  = swz / 98;
  const int qb = swz % 98;
  const int tid = threadIdx.x, lane = tid & 63, w = tid >> 6;
  const int c = lane & 31, hi = lane >> 5;     // q-col / half
  const int wq = w & 1, h = w >> 1;            // q-group (32 rows), key-half (32 keys)
  const int q0 = qb * 64 + wq * 32;

  const __bf16* Qb = Q  + (size_t)b * NN * CI;
  const char*   Kc = (const char*)(Km + (size_t)b * NN * CI);
  const char*   Vc = (const char*)(Vt + (size_t)b * CI * NN);

  __shared__ __align__(16) char sm[65536];     // KL[2]:32KB | VL[2]:32KB ; epilogue scratch

  // staging source addresses (pre-swizzled global so linear LDS == swizzled layout)
  const char* ks[4]; const char* vs[4];
#pragma unroll
  for (int i = 0; i < 4; ++i) {
    int p = i * 4096 + tid * 16;
    int kr = p >> 8, kcl = p & 255;
    ks[i] = Kc + (size_t)kr * 256 + (kcl ^ ((kr & 7) << 4));
    int vr = p >> 7, vcl = p & 127;
    vs[i] = Vc + (size_t)vr * (NN * 2) + (vcl ^ ((vr & 7) << 4));
  }

  auto stage = [&](int bb, int t) {
    size_t ko = (size_t)t << 14;   // t * 16384 B (64 keys * 256B)
    size_t vo = (size_t)t << 7;    // t * 128 B  (64 keys * 2B)
    char* kl = sm + bb * 16384;
    char* vl = sm + 32768 + bb * 16384;
#pragma unroll
    for (int i = 0; i < 4; ++i) {
      gll16(ks[i] + ko, kl + i * 4096 + tid * 16);
      gll16(vs[i] + vo, vl + i * 4096 + tid * 16);
    }
  };

  // Q fragments (B operand): col = lane&31 -> q = q0+c, k = 8*hi + j per 16-ci chunk
  bf16x8 qf[8];
#pragma unroll
  for (int kc = 0; kc < 8; ++kc)
    qf[kc] = *reinterpret_cast<const bf16x8*>(&Qb[(size_t)(q0 + c) * CI + kc * 16 + hi * 8]);

  f32x16 yacc[4] = {};                          // [cb] -> 32 ci each; rows = crow(reg,hi)
  float m_r = -1e30f, l_r = 0.f;                // stats for q = q0 + c (dup across halves)

  stage(0, 0);
  __syncthreads();

  int buf = 0;
  for (int t = 0; t < 98; ++t) {
    if (t + 1 < 98) stage(buf ^ 1, t + 1);
    const char* kl = sm + buf * 16384;
    const char* vl = sm + 32768 + buf * 16384;

    // ---- QK^T swapped: D[key][q], A = K rows (this wave's 32 keys) ----
    f32x16 s = {};
    __builtin_amdgcn_s_setprio(1);
#pragma unroll
    for (int kc = 0; kc < 8; ++kc) {
      bf16x8 kf = *reinterpret_cast<const bf16x8*>(
          kl + (h * 32 + c) * 256 + ((kc * 32 + hi * 16) ^ ((c & 7) << 4)));
      s = __builtin_amdgcn_mfma_f32_32x32x16_bf16(kf, qf[kc], s, 0, 0, 0);
    }
    __builtin_amdgcn_s_setprio(0);

    // ---- softmax: lane holds 16 keys (rows crow(reg,hi)) for q = q0+c ----
    float mx = fmaxf(fmaxf(fmaxf(s[0], s[1]), fmaxf(s[2], s[3])),
                     fmaxf(fmaxf(s[4], s[5]), fmaxf(s[6], s[7])));
    mx = fmaxf(mx, fmaxf(fmaxf(fmaxf(s[8], s[9]), fmaxf(s[10], s[11])),
                         fmaxf(fmaxf(s[12], s[13]), fmaxf(s[14], s[15]))));
    mx = fmaxf(mx, __shfl_xor(mx, 32));

    if (!__all(mx <= m_r + 8.f)) {             // defer-max rescale
      float mnew = fmaxf(m_r, mx);
      float al = exp2f(m_r - mnew);
      m_r = mnew;
      l_r *= al;
      float alr[16];
#pragma unroll
      for (int reg = 0; reg < 16; ++reg)
        alr[reg] = __shfl(al, (reg & 3) + 8 * (reg >> 2) + 4 * hi);
#pragma unroll
      for (int cb = 0; cb < 4; ++cb)
#pragma unroll
        for (int reg = 0; reg < 16; ++reg)
          yacc[cb][reg] *= alr[reg];
    }

    float p[16];
    float ps = 0.f;
#pragma unroll
    for (int reg = 0; reg < 16; ++reg) {
      p[reg] = exp2f(s[reg] - m_r);
      ps += p[reg];
    }
    ps += __shfl_xor(ps, 32);
    l_r += ps;

    // ---- P -> bf16 A-fragments fully in-register ----
    unsigned u[8];
#pragma unroll
    for (int i = 0; i < 8; ++i) u[i] = cvtpk(p[2 * i], p[2 * i + 1]);

    __builtin_amdgcn_s_setprio(1);
#pragma unroll
    for (int ch = 0; ch < 2; ++ch) {
      const unsigned* cu = &u[ch * 4];
      unsigned sA = (unsigned)__shfl_xor((int)(hi ? cu[0] : cu[2]), 32);
      unsigned sB = (unsigned)__shfl_xor((int)(hi ? cu[1] : cu[3]), 32);
      union { unsigned uu[4]; bf16x8 v; } pk_;
      pk_.uu[0] = hi ? sA : cu[0];
      pk_.uu[1] = hi ? sB : cu[1];
      pk_.uu[2] = hi ? cu[2] : sA;
      pk_.uu[3] = hi ? cu[3] : sB;
#pragma unroll
      for (int cb = 0; cb < 4; ++cb) {
        bf16x8 vf = *reinterpret_cast<const bf16x8*>(
            vl + (cb * 32 + c) * 128 + ((h * 64 + ch * 32 + hi * 16) ^ ((c & 7) << 4)));
        yacc[cb] = __builtin_amdgcn_mfma_f32_32x32x16_bf16(pk_.v, vf, yacc[cb], 0, 0, 0);
      }
    }
    __builtin_amdgcn_s_setprio(0);

    __syncthreads();
    buf ^= 1;
  }

  // ---- merge key-halves: waves (wq,h=1) -> LDS, (wq,h=0) merges + stores ----
  float* scr = (float*)sm;
  if (h == 1) {
    float* base = scr + wq * 4096;             // 16KB per q-group
#pragma unroll
    for (int cb = 0; cb < 4; ++cb)
#pragma unroll
      for (int reg = 0; reg < 16; ++reg)
        base[(cb * 16 + reg) * 64 + lane] = yacc[cb][reg];
    float* ml = scr + 8192 + wq * 128;
    ml[lane] = m_r;
    ml[64 + lane] = l_r;
  }
  __syncthreads();
  if (h == 0) {
    const float* base = scr + wq * 4096;
    const float* ml = scr + 8192 + wq * 128;
    float mB = ml[lane], lB = ml[64 + lane];
    float mM = fmaxf(m_r, mB);
    float fA = exp2f(m_r - mM);
    float fB = exp2f(mB - mM);
    float il = 1.f / (l_r * fA + lB * fB);
    float faq[16], fbq[16], ilq[16];
#pragma unroll
    for (int reg = 0; reg < 16; ++reg) {
      int qloc = (reg & 3) + 8 * (reg >> 2) + 4 * hi;
      faq[reg] = __shfl(fA, qloc);
      fbq[reg] = __shfl(fB, qloc);
      ilq[reg] = __shfl(il, qloc);
    }
#pragma unroll
    for (int cb = 0; cb < 4; ++cb) {
#pragma unroll
      for (int reg = 0; reg < 16; ++reg) {
        int qloc = (reg & 3) + 8 * (reg >> 2) + 4 * hi;
        float v = (yacc[cb][reg] * faq[reg] + base[(cb * 16 + reg) * 64 + lane] * fbq[reg]) * ilq[reg];
        Y[((size_t)b * NN + q0 + qloc) * CI + cb * 32 + c] = (__bf16)v;
      }
    }
  }
}

// ---------------- output: z = (Ww @ y)*scale + shift + x ----------------
__launch_bounds__(256)
__global__ void nlb_out(const __bf16* __restrict__ Y, const __bf16* __restrict__ wwb,
                        const float* __restrict__ scale, const float* __restrict__ shift,
                        const float* __restrict__ x, float* __restrict__ out) {
  const int nb = blockIdx.x;
  const int mb = blockIdx.y;
  const int b  = blockIdx.z;
  const int tid = threadIdx.x, lane = tid & 63, w = tid >> 6;
  const int r = lane & 15, g = lane >> 4;
  const int n0 = nb * 64, c0 = mb * 64 + w * 16;

  const __bf16* Yb = Y + (size_t)b * NN * CI;
  f32x4 acc[4] = {};
#pragma unroll
  for (int k0 = 0; k0 < 128; k0 += 32) {
    bf16x8 af = *reinterpret_cast<const bf16x8*>(&wwb[(size_t)(c0 + r) * CI + k0 + g * 8]);
#pragma unroll
    for (int j = 0; j < 4; ++j) {
      bf16x8 bfg = *reinterpret_cast<const bf16x8*>(
          &Yb[(size_t)(n0 + j * 16 + r) * CI + k0 + g * 8]);
      acc[j] = __builtin_amdgcn_mfma_f32_16x16x32_bf16(af, bfg, acc[j], 0, 0, 0);
    }
  }
  const float* xb = x + (size_t)b * CC * NN;
  float* ob = out + (size_t)b * CC * NN;
#pragma unroll
  for (int j = 0; j < 4; ++j) {
    int n = n0 + j * 16 + r;
#pragma unroll
    for (int reg = 0; reg < 4; ++reg) {
      int cc = c0 + g * 4 + reg;
      size_t off = (size_t)cc * NN + n;
      ob[off] = acc[j][reg] * scale[cc] + shift[cc] + xb[off];
    }
  }
}

extern "C" void kernel_launch(void* const* d_in, const int* in_sizes, int n_in,
                              void* d_out, int out_size, void* d_ws, size_t ws_size,
                              hipStream_t stream) {
  (void)in_sizes; (void)n_in; (void)out_size; (void)ws_size;
  const float* x     = (const float*)d_in[0];
  const float* Wg    = (const float*)d_in[1];
  const float* bg    = (const float*)d_in[2];
  const float* Wt    = (const float*)d_in[3];
  const float* bt    = (const float*)d_in[4];
  const float* Wp    = (const float*)d_in[5];
  const float* bp    = (const float*)d_in[6];
  const float* Ww    = (const float*)d_in[7];
  const float* bw    = (const float*)d_in[8];
  const float* gamma = (const float*)d_in[9];
  const float* beta  = (const float*)d_in[10];
  const float* rmean = (const float*)d_in[11];
  const float* rvar  = (const float*)d_in[12];
  float* out = (float*)d_out;

  char* ws = (char*)d_ws;
  __bf16* wall = (__bf16*)(ws + 0);
  float*  ball = (float*)(ws + 196608);
  __bf16* wwb  = (__bf16*)(ws + 198144);
  float*  scl  = (float*)(ws + 263680);
  float*  shf  = (float*)(ws + 264704);
  __bf16* Qw   = (__bf16*)(ws + 265728);
  __bf16* Kw   = (__bf16*)(ws + 265728 + 6422528ull);
  __bf16* Vw   = (__bf16*)(ws + 265728 + 2ull * 6422528ull);
  __bf16* Yw   = (__bf16*)(ws + 265728 + 3ull * 6422528ull);

  nlb_prep<<<513, 256, 0, stream>>>(Wg, bg, Wt, bt, Wp, bp, Ww, bw, gamma, beta,
                                    rmean, rvar, wall, ball, wwb, scl, shf);
  nlb_proj<<<dim3(98, 6, 4), 256, 0, stream>>>(x, wall, ball, Qw, Kw, Vw);
  nlb_attn<<<392, 256, 0, stream>>>(Qw, Kw, Vw, Yw);
  nlb_out<<<dim3(98, 4, 4), 256, 0, stream>>>(Yw, wwb, scl, shf, x, out);
}